// Round 18
// baseline (106.544 us; speedup 1.0000x reference)
//
#include <hip/hip_runtime.h>
#include <hip/hip_bf16.h>

#define B_ROWS 32768

typedef unsigned short u16;
typedef unsigned int u32;
typedef float f32x4 __attribute__((ext_vector_type(4)));
typedef __bf16 bf16x8 __attribute__((ext_vector_type(8)));

__device__ __forceinline__ u16 f2bf(float f){
    union { float f; u32 u; } v; v.f = f;
    return (u16)((v.u + 0x7FFFu + ((v.u >> 16) & 1u)) >> 16);
}
__device__ __forceinline__ float bf2f(u16 h){
    union { u32 u; float f; } v; v.u = ((u32)h) << 16; return v.f;
}
__device__ __forceinline__ u32 cvtpk(float lo, float hi){
    u32 r;
    asm("v_cvt_pk_bf16_f32 %0, %1, %2" : "=v"(r) : "v"(lo), "v"(hi));
    return r;
}
__device__ __forceinline__ void async_cp16(void* lds_dst, const void* g_src){
    __builtin_amdgcn_global_load_lds(
        (const __attribute__((address_space(1))) unsigned int*)g_src,
        (__attribute__((address_space(3))) unsigned int*)lds_dst, 16, 0, 0);
}

// ---------------- weight cast/transpose into staging-friendly images ----------
__global__ void cast_weights_kernel(const float* __restrict__ proj_w,
                                    const float* __restrict__ exp_w1,
                                    const float* __restrict__ exp_w2,
                                    const float* __restrict__ pre_w,
                                    const float* __restrict__ gate_w,
                                    u16* __restrict__ pimg, u16* __restrict__ w1img,
                                    u16* __restrict__ w2img, u16* __restrict__ prwT,
                                    u16* __restrict__ gwimg){
    int i = blockIdx.x * 256 + threadIdx.x;
    if (i < 294912){                       // pimg (BK=32 chunks)
        int m = i / 98304, r = i % 98304;
        int c = r / 4096, rr = r % 4096;
        int col = rr >> 5, kk = rr & 31;
        int kb = kk ^ (((col >> 1) & 3) << 3);
        pimg[i] = f2bf(proj_w[m*98304 + (c*32 + kb)*128 + col]);
    } else if (i < 688128){                // w1img
        int j = i - 294912;
        int e = j / 49152, r = j % 49152;
        int ph = r / 4096, rr = r % 4096;
        int q = rr >> 10, col = (rr >> 3) & 127, el = rr & 7;
        w1img[j] = f2bf(exp_w1[e*49152 + (ph*32 + q*8 + el)*128 + col]);
    } else if (i < 819200){                // w2img
        int j = i - 688128;
        int e = j / 16384, r = j % 16384;
        int c2 = r / 4096, rr = r % 4096;
        int q = rr >> 10, col = (rr >> 3) & 127, el = rr & 7;
        w2img[j] = f2bf(exp_w2[e*16384 + (c2*32 + q*8 + el)*128 + col]);
    } else if (i < 827392){                // prwT
        int j = i - 819200;
        int o = j / 128, k = j % 128;
        prwT[j] = f2bf(pre_w[k*64 + o]);
    } else if (i < 833536){                // gwimg
        int j = i - 827392;
        int e = j / 384, k = j % 384;
        gwimg[j] = (e < 8) ? f2bf(gate_w[k*8 + e]) : (u16)0;
    }
}

// ---------------- fully fused: proj + gate + experts + pre + head -------------
// 256 blocks x 512 threads (8 waves 4x2), 128 rows/block, 1 block/CU.
// Phase A: 36 GROUPS of 2 chunks, 2 slot-PAIRS (A 2x32K, B 2x16K),
//   consume -> barrier -> stage G+2 into G's pair -> vmcnt(6) -> barrier
//   (phase-C-proven order; fixes r17's ring-overlap race).
// Gate from xreg at A/C boundary; phase C = r16 verbatim.
#define XSL      0          // 32 KB per-modality x slice
#define A2       32768      // 4 x 16 KB A-feat (2 pairs)
#define B2       98304      // 4 x 8 KB pimg (2 pairs) -> 131072
// phase C overlay:
#define HS2      0          // 128 x 256B XOR-swizzled = 32768
#define GWT2     32768      // f32 [8][128] = 4096
#define B1_2     36864      // bf16 [8][128] = 2048
#define B2_2     38912      // bf16 [8][128] = 2048
#define WB2      40960      // 2 x 24576 group ring -> 90112

__global__ __launch_bounds__(512, 1) void fused_kernel(
    const float* __restrict__ ft, const float* __restrict__ fa, const float* __restrict__ fv,
    const u16* __restrict__ pimg, const float* __restrict__ proj_b,
    const u16* __restrict__ w1img, const u16* __restrict__ w2img,
    const u16* __restrict__ prwT, const u16* __restrict__ gwimg,
    const float* __restrict__ gate_b, const float* __restrict__ exp_b1, const float* __restrict__ exp_b2,
    const float* __restrict__ pre_b, const float* __restrict__ head_w, const float* __restrict__ head_b,
    float* __restrict__ out)
{
    __shared__ __align__(16) char lds[163840];
    const int tid = threadIdx.x;
    const int lane = tid & 63, wid = tid >> 6;   // 8 waves
    const int wr = wid >> 1, wc = wid & 1;       // 4 x 2
    const int lr = lane & 15, q = lane >> 4;
    const int blk = blockIdx.x;
    const int row0 = blk * 128;
    const char* w1b = (const char*)w1img;
    const char* w2b = (const char*)w2img;
    char* HsB = lds + HS2;
    u16* b1L = (u16*)(lds + B1_2);
    u16* b2L = (u16*)(lds + B2_2);

    // ---- prologue: proj_b -> registers, drain so pipeline counts are exact ----
    float pb0[4], pb1[4], pb2[4];
    #pragma unroll
    for (int ni = 0; ni < 4; ni++){
        int c = wc*64 + ni*16 + lr;
        pb0[ni] = proj_b[c];
        pb1[ni] = proj_b[128 + c];
        pb2[ni] = proj_b[256 + c];
    }
    asm volatile("s_waitcnt vmcnt(0)" ::: "memory");

    // A staging source offsets (XOR-pre-swizzled global addresses, linear LDS dst)
    u32 aoffs[2];
    #pragma unroll
    for (int i = 0; i < 2; i++){
        int P = i*8192 + tid*16;
        int row = P >> 7, inner = P & 127;
        aoffs[i] = (u32)((row0 + row)*3072 + (inner ^ ((row & 7) << 4)));
    }

    bf16x8 xreg[12][2];

// stage one GROUP (2 chunks) into pair (G&1): 6 async ops, fixed order
#define STAGE_GROUP(G) do{                                                     \
        int mm_ = (G)/12, kk0_ = ((G)%12)*2;                                   \
        const char* ab_ = (const char*)(mm_ == 0 ? ft : mm_ == 1 ? fa : fv);   \
        int sb_ = ((G)&1)*2;                                                   \
        char* a0_ = lds + A2 + sb_*16384 + tid*16;                             \
        char* a1_ = a0_ + 16384;                                               \
        const char* bs_ = (const char*)pimg + mm_*196608 + kk0_*8192 + tid*16; \
        async_cp16(a0_,        ab_ + aoffs[0] + kk0_*128);                     \
        async_cp16(a0_ + 8192, ab_ + aoffs[1] + kk0_*128);                     \
        async_cp16(lds + B2 + sb_*8192 + tid*16, bs_);                         \
        async_cp16(a1_,        ab_ + aoffs[0] + (kk0_+1)*128);                 \
        async_cp16(a1_ + 8192, ab_ + aoffs[1] + (kk0_+1)*128);                 \
        async_cp16(lds + B2 + (sb_+1)*8192 + tid*16, bs_ + 8192);              \
    }while(0)

#define CONSUME1(c) do{                                                        \
        int sl_ = (((c) >> 1) & 1)*2 + ((c) & 1);                              \
        const char* Abuf = lds + A2 + sl_*16384;                               \
        const char* Bbuf = lds + B2 + sl_*8192;                                \
        bf16x8 af[2];                                                          \
        _Pragma("unroll")                                                      \
        for (int mi = 0; mi < 2; mi++){                                        \
            int row = wr*32 + mi*16 + lr;                                      \
            int aoff = row*128 + ((q*32) ^ ((row & 7) << 4));                  \
            f32x4 a0 = *(const f32x4*)(Abuf + aoff);                           \
            f32x4 a1 = *(const f32x4*)(Abuf + (aoff ^ 16));                    \
            union { u32 w[4]; bf16x8 v; } u;                                   \
            u.w[0] = cvtpk(a0.x, a0.y); u.w[1] = cvtpk(a0.z, a0.w);            \
            u.w[2] = cvtpk(a1.x, a1.y); u.w[3] = cvtpk(a1.z, a1.w);            \
            af[mi] = u.v;                                                      \
        }                                                                      \
        __builtin_amdgcn_s_setprio(1);                                         \
        _Pragma("unroll")                                                      \
        for (int ni = 0; ni < 4; ni++){                                        \
            int col = wc*64 + ni*16 + lr;                                      \
            int boff = col*64 + ((q*16) ^ (((col >> 1) & 3) << 4));            \
            bf16x8 bf = *(const bf16x8*)(Bbuf + boff);                         \
            acc[0][ni] = __builtin_amdgcn_mfma_f32_16x16x32_bf16(af[0], bf, acc[0][ni], 0, 0, 0); \
            acc[1][ni] = __builtin_amdgcn_mfma_f32_16x16x32_bf16(af[1], bf, acc[1][ni], 0, 0, 0); \
        }                                                                      \
        __builtin_amdgcn_s_setprio(0);                                         \
    }while(0)

// one modality: 12 groups (consume -> barrier -> stage -> counted wait -> barrier)
#define PHASE_A_MOD(MC, PB) do{                                                \
        _Pragma("unroll 1")                                                    \
        for (int grp = 0; grp < 12; grp++){                                    \
            int G = MC*12 + grp;                                               \
            __builtin_amdgcn_sched_barrier(0);                                 \
            CONSUME1(2*G);                                                     \
            CONSUME1(2*G + 1);                                                 \
            __builtin_amdgcn_sched_barrier(0);                                 \
            __builtin_amdgcn_s_barrier();      /* all waves done reading pair */ \
            if (MC < 2 || grp < 10){                                           \
                STAGE_GROUP(G + 2);            /* same pair as G: reads done */ \
                asm volatile("s_waitcnt vmcnt(6)" ::: "memory");  /* G+1 in */ \
            } else {                                                           \
                asm volatile("s_waitcnt vmcnt(0)" ::: "memory");               \
            }                                                                  \
            __builtin_amdgcn_s_barrier();      /* G+1 visible to all */        \
            __builtin_amdgcn_sched_barrier(0);                                 \
        }                                                                      \
        /* slice epilogue: acc(+bias) -> 32K slice */                          \
        _Pragma("unroll")                                                      \
        for (int mi = 0; mi < 2; mi++)                                         \
            _Pragma("unroll")                                                  \
            for (int ni = 0; ni < 4; ni++){                                    \
                int lcol = wc*64 + ni*16 + lr;                                 \
                int ktL = lcol >> 5, qI = (lcol >> 3) & 3, el = lcol & 7;      \
                _Pragma("unroll")                                              \
                for (int j = 0; j < 4; j++){                                   \
                    int row = wr*32 + mi*16 + q*4 + j;                         \
                    *(u16*)(lds + XSL + (row >> 6)*16384 + ktL*4096 + qI*1024  \
                            + (row & 63)*16 + el*2) = f2bf(acc[mi][ni][j] + PB[ni]); \
                    acc[mi][ni][j] = 0.f;                                      \
                }                                                              \
            }                                                                  \
        asm volatile("s_waitcnt lgkmcnt(0)" ::: "memory");                     \
        __builtin_amdgcn_sched_barrier(0);                                     \
        __builtin_amdgcn_s_barrier();                                          \
        {   /* incremental xreg preload for this modality */                   \
            const char* xa0 = lds + XSL + (wr >> 1)*16384 + q*1024;            \
            _Pragma("unroll")                                                  \
            for (int ph = 0; ph < 4; ph++){                                    \
                xreg[MC*4 + ph][0] = *(const bf16x8*)(xa0 + ph*4096 + ((wr & 1)*32 + lr)*16);      \
                xreg[MC*4 + ph][1] = *(const bf16x8*)(xa0 + ph*4096 + ((wr & 1)*32 + 16 + lr)*16); \
            }                                                                  \
        }                                                                      \
        asm volatile("s_waitcnt lgkmcnt(0)" ::: "memory");                     \
    }while(0)

    f32x4 acc[2][4];
    #pragma unroll
    for (int i = 0; i < 2; i++)
        #pragma unroll
        for (int j = 0; j < 4; j++) acc[i][j] = {0.f, 0.f, 0.f, 0.f};

    STAGE_GROUP(0);
    STAGE_GROUP(1);
    asm volatile("s_waitcnt vmcnt(6)" ::: "memory");   // G0 landed
    __builtin_amdgcn_sched_barrier(0);
    __builtin_amdgcn_s_barrier();                      // G0 visible
    PHASE_A_MOD(0, pb0);
    PHASE_A_MOD(1, pb1);
    PHASE_A_MOD(2, pb2);
#undef STAGE_GROUP
#undef CONSUME1
#undef PHASE_A_MOD
    // past the m=2 epilogue barrier: A2/B2 dead, no VMEM outstanding, xreg complete

    // ---- gate from xreg (A-operand) + gwimg fragments (global) ----
    float gw4a[4], gw4b[4];
    {
        f32x4 ga0 = {0.f,0.f,0.f,0.f}, ga1 = {0.f,0.f,0.f,0.f};
        const u16* gwp = gwimg + lr*384 + q*8;
        #pragma unroll
        for (int ph = 0; ph < 12; ph++){
            bf16x8 gb = *(const bf16x8*)(gwp + ph*32);
            ga0 = __builtin_amdgcn_mfma_f32_16x16x32_bf16(xreg[ph][0], gb, ga0, 0, 0, 0);
            ga1 = __builtin_amdgcn_mfma_f32_16x16x32_bf16(xreg[ph][1], gb, ga1, 0, 0, 0);
        }
        float gbv = gate_b[lr & 7];
        #pragma unroll
        for (int j = 0; j < 4; j++){
            float v = ga0[j] + gbv;
            float mx = v;
            mx = fmaxf(mx, __shfl_xor(mx, 1));
            mx = fmaxf(mx, __shfl_xor(mx, 2));
            mx = fmaxf(mx, __shfl_xor(mx, 4));
            float s = __expf(v - mx);
            float t = s;
            t += __shfl_xor(t, 1); t += __shfl_xor(t, 2); t += __shfl_xor(t, 4);
            gw4a[j] = s / t;
            float v1 = ga1[j] + gbv;
            float mx1 = v1;
            mx1 = fmaxf(mx1, __shfl_xor(mx1, 1));
            mx1 = fmaxf(mx1, __shfl_xor(mx1, 2));
            mx1 = fmaxf(mx1, __shfl_xor(mx1, 4));
            float s1 = __expf(v1 - mx1);
            float t1 = s1;
            t1 += __shfl_xor(t1, 1); t1 += __shfl_xor(t1, 2); t1 += __shfl_xor(t1, 4);
            gw4b[j] = s1 / t1;
        }
    }

    // ---- phase-C group staging: uniform 3 async_cp16 per group ----
#define WGROUP_STAGE2(gg2, sl) do{                                             \
        int e2_ = (gg2) / 6, i2_ = (gg2) % 6;                                  \
        char* dst_ = lds + WB2 + (sl)*24576 + tid*16;                          \
        if (i2_ < 4){                                                          \
            const char* src_ = w1b + e2_*98304 + i2_*24576 + tid*16;           \
            async_cp16(dst_,         src_);                                    \
            async_cp16(dst_ + 8192,  src_ + 8192);                             \
            async_cp16(dst_ + 16384, src_ + 16384);                            \
        } else {                                                               \
            const char* src_ = w2b + e2_*32768 + (i2_ - 4)*16384 + tid*16;     \
            async_cp16(dst_,         src_);                                    \
            async_cp16(dst_ + 8192,  src_ + 8192);                             \
            async_cp16(dst_ + 16384, src_);   /* dup: uniform vmcnt */         \
        }                                                                      \
    }while(0)

    // GWT/biases + prefetch groups 0,1
    if (wc == 0 && lr < 8){
        f32x4 wa = {gw4a[0], gw4a[1], gw4a[2], gw4a[3]};
        f32x4 wb = {gw4b[0], gw4b[1], gw4b[2], gw4b[3]};
        *(f32x4*)(lds + GWT2 + lr*512 + (wr*32 + q*4)*4) = wa;
        *(f32x4*)(lds + GWT2 + lr*512 + (wr*32 + 16 + q*4)*4) = wb;
    }
    for (int i = tid; i < 1024; i += 512){
        b1L[i] = f2bf(exp_b1[i]);
        b2L[i] = f2bf(exp_b2[i]);
    }
    WGROUP_STAGE2(0, 0);
    WGROUP_STAGE2(1, 1);
    asm volatile("s_waitcnt vmcnt(0) lgkmcnt(0)" ::: "memory");
    __builtin_amdgcn_sched_barrier(0);
    __builtin_amdgcn_s_barrier();

    // ---- phase C: 48 groups, 2-slot ring, counted vmcnt(3) — never drains ----
    f32x4 fus[2][4];
    #pragma unroll
    for (int i = 0; i < 2; i++)
        #pragma unroll
        for (int j = 0; j < 4; j++) fus[i][j] = {0.f, 0.f, 0.f, 0.f};

    #pragma unroll 1
    for (int e = 0; e < 8; e++){
        f32x4 ac1[2][4];
        #pragma unroll
        for (int i = 0; i < 2; i++)
            #pragma unroll
            for (int j = 0; j < 4; j++) ac1[i][j] = {0.f, 0.f, 0.f, 0.f};

        #pragma unroll                                     // xreg[ph] static
        for (int grp = 0; grp < 4; grp++){
            int g = e*6 + grp;
            const char* wbase = lds + WB2 + (g & 1)*24576;
            __builtin_amdgcn_s_setprio(1);
            #pragma unroll
            for (int c = 0; c < 3; c++){
                int ph = grp*3 + c;
                const char* wsl = wbase + c*8192 + q*2048;
                #pragma unroll
                for (int ni = 0; ni < 4; ni++){
                    bf16x8 bf = *(const bf16x8*)(wsl + (wc*64 + ni*16 + lr)*16);
                    ac1[0][ni] = __builtin_amdgcn_mfma_f32_16x16x32_bf16(xreg[ph][0], bf, ac1[0][ni], 0, 0, 0);
                    ac1[1][ni] = __builtin_amdgcn_mfma_f32_16x16x32_bf16(xreg[ph][1], bf, ac1[1][ni], 0, 0, 0);
                }
            }
            __builtin_amdgcn_s_setprio(0);
            if (grp == 3){
                // h = relu(ac1 + b1) -> Hs (XOR-swizzled)
                #pragma unroll
                for (int mi = 0; mi < 2; mi++)
                    #pragma unroll
                    for (int ni = 0; ni < 4; ni++){
                        int col = wc*64 + ni*16 + lr;
                        float b1v = bf2f(b1L[e*128 + col]);
                        #pragma unroll
                        for (int j = 0; j < 4; j++){
                            int row = wr*32 + mi*16 + q*4 + j;
                            *(u16*)(HsB + row*256 + ((col*2) ^ ((row & 7) << 4)))
                                = f2bf(fmaxf(ac1[mi][ni][j] + b1v, 0.f));
                        }
                    }
                asm volatile("s_waitcnt lgkmcnt(0)" ::: "memory");
            }
            __builtin_amdgcn_sched_barrier(0);
            __builtin_amdgcn_s_barrier();                  // slot reads + Hs writes done
            {
                int gn = g + 2;
                if (gn < 48){
                    WGROUP_STAGE2(gn, gn & 1);
                    asm volatile("s_waitcnt vmcnt(3)" ::: "memory");   // g+1 landed
                } else {
                    asm volatile("s_waitcnt vmcnt(0)" ::: "memory");
                }
            }
            __builtin_amdgcn_s_barrier();                  // next group + Hs visible
            __builtin_amdgcn_sched_barrier(0);
        }

        f32x4 ac2[2][4];
        #pragma unroll
        for (int i = 0; i < 2; i++)
            #pragma unroll
            for (int j = 0; j < 4; j++) ac2[i][j] = {0.f, 0.f, 0.f, 0.f};

        #pragma unroll 1
        for (int grp = 0; grp < 2; grp++){
            int g = e*6 + 4 + grp;
            const char* wbase = lds + WB2 + (g & 1)*24576;
            #pragma unroll
            for (int c = 0; c < 2; c++){
                int p2 = grp*2 + c;
                const char* wsl = wbase + c*8192 + q*2048;
                int cb = p2*64 + q*16;
                int rowA = wr*32 + lr;
                int rowB = wr*32 + 16 + lr;
                bf16x8 af0 = *(const bf16x8*)(HsB + rowA*256 + (cb ^ ((rowA & 7) << 4)));
                bf16x8 af1 = *(const bf16x8*)(HsB + rowB*256 + (cb ^ ((rowB & 7) << 4)));
                __builtin_amdgcn_s_setprio(1);
                #pragma unroll
                for (int ni = 0; ni < 4; ni++){
                    bf16x8 bf = *(const bf16x8*)(wsl + (wc*64 + ni*16 + lr)*16);
                    ac2[0][ni] = __builtin_amdgcn_mfma_f32_16x16x32_bf16(af0, bf, ac2[0][ni], 0, 0, 0);
                    ac2[1][ni] = __builtin_amdgcn_mfma_f32_16x16x32_bf16(af1, bf, ac2[1][ni], 0, 0, 0);
                }
                __builtin_amdgcn_s_setprio(0);
            }
            __builtin_amdgcn_sched_barrier(0);
            __builtin_amdgcn_s_barrier();                  // slot reads done
            {
                int gn = g + 2;
                if (gn < 48){
                    WGROUP_STAGE2(gn, gn & 1);
                    asm volatile("s_waitcnt vmcnt(3)" ::: "memory");
                } else {
                    asm volatile("s_waitcnt vmcnt(0)" ::: "memory");
                }
            }
            __builtin_amdgcn_s_barrier();
            __builtin_amdgcn_sched_barrier(0);
        }
        // fused += gw[:,e] * (eo + b2)
        #pragma unroll
        for (int mi = 0; mi < 2; mi++){
            f32x4 gwv = *(const f32x4*)(lds + GWT2 + e*512 + (wr*32 + mi*16 + q*4)*4);
            #pragma unroll
            for (int ni = 0; ni < 4; ni++){
                int col = wc*64 + ni*16 + lr;
                float b2v = bf2f(b2L[e*128 + col]);
                #pragma unroll
                for (int j = 0; j < 4; j++)
                    fus[mi][ni][j] += gwv[j] * (ac2[mi][ni][j] + b2v);
            }
        }
    }
#undef WGROUP_STAGE2

    __builtin_amdgcn_sched_barrier(0);
    __builtin_amdgcn_s_barrier();                      // all Hs(h7) reads done
    // fused -> Hs (bf16, XOR-swizzled)
    #pragma unroll
    for (int mi = 0; mi < 2; mi++)
        #pragma unroll
        for (int ni = 0; ni < 4; ni++){
            int col = wc*64 + ni*16 + lr;
            #pragma unroll
            for (int j = 0; j < 4; j++){
                int row = wr*32 + mi*16 + q*4 + j;
                *(u16*)(HsB + row*256 + ((col*2) ^ ((row & 7) << 4))) = f2bf(fus[mi][ni][j]);
            }
        }
    asm volatile("s_waitcnt lgkmcnt(0)" ::: "memory");
    __builtin_amdgcn_sched_barrier(0);
    __builtin_amdgcn_s_barrier();

    // ---- penult = relu(fused @ pre_w + pre_b): wave wid -> rows wid*16..+16 ----
    f32x4 ap[4];
    #pragma unroll
    for (int i = 0; i < 4; i++) ap[i] = {0.f, 0.f, 0.f, 0.f};
    #pragma unroll
    for (int kt = 0; kt < 4; kt++){
        int row = wid*16 + lr;
        int cb = kt*64 + q*16;
        bf16x8 af = *(const bf16x8*)(HsB + row*256 + (cb ^ ((row & 7) << 4)));
        #pragma unroll
        for (int ni = 0; ni < 4; ni++){
            bf16x8 bf = *(const bf16x8*)(prwT + (size_t)(ni*16 + lr)*128 + kt*32 + q*8);
            ap[ni] = __builtin_amdgcn_mfma_f32_16x16x32_bf16(af, bf, ap[ni], 0, 0, 0);
        }
    }
    float* Pen = (float*)(lds + WB2);   // [128][68], WB region dead
    #pragma unroll
    for (int ni = 0; ni < 4; ni++){
        int col = ni*16 + lr;
        float pbv = pre_b[col];
        #pragma unroll
        for (int j = 0; j < 4; j++){
            int row = wid*16 + q*4 + j;
            Pen[row*68 + col] = fmaxf(ap[ni][j] + pbv, 0.f);
        }
    }
    asm volatile("s_waitcnt lgkmcnt(0)" ::: "memory");
    __builtin_amdgcn_sched_barrier(0);
    __builtin_amdgcn_s_barrier();
    // ---- head ----
    if (tid < 256){
        int r = tid >> 1, c = tid & 1;
        float s = head_b[c];
        #pragma unroll 8
        for (int k = 0; k < 64; k++) s += Pen[r*68 + k] * head_w[k*2 + c];
        out[(size_t)(blk*128 + r)*2 + c] = s;
    }
}

extern "C" void kernel_launch(void* const* d_in, const int* in_sizes, int n_in,
                              void* d_out, int out_size, void* d_ws, size_t ws_size,
                              hipStream_t stream) {
    const float* ft     = (const float*)d_in[0];
    const float* fa     = (const float*)d_in[1];
    const float* fv     = (const float*)d_in[2];
    const float* proj_w = (const float*)d_in[3];
    const float* proj_b = (const float*)d_in[4];
    const float* exp_w1 = (const float*)d_in[5];
    const float* exp_b1 = (const float*)d_in[6];
    const float* exp_w2 = (const float*)d_in[7];
    const float* exp_b2 = (const float*)d_in[8];
    const float* gate_w = (const float*)d_in[9];
    const float* gate_b = (const float*)d_in[10];
    const float* pre_w  = (const float*)d_in[11];
    const float* pre_b  = (const float*)d_in[12];
    const float* head_w = (const float*)d_in[13];
    const float* head_b = (const float*)d_in[14];
    float* out = (float*)d_out;

    u16* pimg  = (u16*)d_ws;                      // 294912
    u16* w1img = pimg + 294912;                   // 393216
    u16* w2img = w1img + 393216;                  // 131072
    u16* prwT  = w2img + 131072;                  // 8192
    u16* gwimg = prwT + 8192;                     // 6144

    cast_weights_kernel<<<3256, 256, 0, stream>>>(proj_w, exp_w1, exp_w2, pre_w, gate_w,
                                                  pimg, w1img, w2img, prwT, gwimg);
    fused_kernel<<<256, 512, 0, stream>>>(ft, fa, fv, pimg, proj_b,
                                          w1img, w2img, prwT, gwimg,
                                          gate_b, exp_b1, exp_b2,
                                          pre_b, head_w, head_b, out);
}

// Round 19
// 102.993 us; speedup vs baseline: 1.0345x; 1.0345x over previous
//
#include <hip/hip_runtime.h>
#include <hip/hip_bf16.h>

#define B_ROWS 32768

typedef unsigned short u16;
typedef unsigned int u32;
typedef float f32x4 __attribute__((ext_vector_type(4)));
typedef __bf16 bf16x8 __attribute__((ext_vector_type(8)));

__device__ __forceinline__ u16 f2bf(float f){
    union { float f; u32 u; } v; v.f = f;
    return (u16)((v.u + 0x7FFFu + ((v.u >> 16) & 1u)) >> 16);
}
__device__ __forceinline__ float bf2f(u16 h){
    union { u32 u; float f; } v; v.u = ((u32)h) << 16; return v.f;
}
__device__ __forceinline__ u32 cvtpk(float lo, float hi){
    u32 r;
    asm("v_cvt_pk_bf16_f32 %0, %1, %2" : "=v"(r) : "v"(lo), "v"(hi));
    return r;
}
__device__ __forceinline__ void async_cp16(void* lds_dst, const void* g_src){
    __builtin_amdgcn_global_load_lds(
        (const __attribute__((address_space(1))) unsigned int*)g_src,
        (__attribute__((address_space(3))) unsigned int*)lds_dst, 16, 0, 0);
}

// ---------------- weight cast/transpose into staging-friendly images ----------
__global__ void cast_weights_kernel(const float* __restrict__ proj_w,
                                    const float* __restrict__ exp_w1,
                                    const float* __restrict__ exp_w2,
                                    const float* __restrict__ pre_w,
                                    const float* __restrict__ gate_w,
                                    u16* __restrict__ pimg, u16* __restrict__ w1img,
                                    u16* __restrict__ w2img, u16* __restrict__ prwT,
                                    u16* __restrict__ gwimg){
    int i = blockIdx.x * 256 + threadIdx.x;
    if (i < 294912){                       // pimg (BK=32 chunks)
        int m = i / 98304, r = i % 98304;
        int c = r / 4096, rr = r % 4096;
        int col = rr >> 5, kk = rr & 31;
        int kb = kk ^ (((col >> 1) & 3) << 3);
        pimg[i] = f2bf(proj_w[m*98304 + (c*32 + kb)*128 + col]);
    } else if (i < 688128){                // w1img
        int j = i - 294912;
        int e = j / 49152, r = j % 49152;
        int ph = r / 4096, rr = r % 4096;
        int q = rr >> 10, col = (rr >> 3) & 127, el = rr & 7;
        w1img[j] = f2bf(exp_w1[e*49152 + (ph*32 + q*8 + el)*128 + col]);
    } else if (i < 819200){                // w2img
        int j = i - 688128;
        int e = j / 16384, r = j % 16384;
        int c2 = r / 4096, rr = r % 4096;
        int q = rr >> 10, col = (rr >> 3) & 127, el = rr & 7;
        w2img[j] = f2bf(exp_w2[e*16384 + (c2*32 + q*8 + el)*128 + col]);
    } else if (i < 827392){                // prwT
        int j = i - 819200;
        int o = j / 128, k = j % 128;
        prwT[j] = f2bf(pre_w[k*64 + o]);
    } else if (i < 833536){                // gwimg
        int j = i - 827392;
        int e = j / 384, k = j % 384;
        gwimg[j] = (e < 8) ? f2bf(gate_w[k*8 + e]) : (u16)0;
    }
}

// ---------------- fully fused: proj + gate + experts + pre + head -------------
// 256 blocks x 512 threads (8 waves 4x2), 128 rows/block, 1 block/CU, 160KB LDS.
// Phase A: r16-verbatim depth-2 pipeline (A 3-slot ring, B 2-slot, vmcnt(5)).
// Phase C: x-in-registers + 24 GROUPS of 6 chunks (2x48K ring, uniform 6-op
//   staging, vmcnt(6)) — barrier pairs 48 -> 24, never drains until tail.
#define A_OFF    98304      // phase A: 3 x 16 KB A-feat ring
#define B_OFF    147456     // phase A: 2 x 8 KB pimg ring -> 163840
// phase C overlay (entire LDS dead after xreg preload + gate):
#define HS2      0          // 128 x 256B XOR-swizzled = 32768
#define GWT2     32768      // f32 [8][128] = 4096
#define B1_2     36864      // bf16 [8][128] = 2048
#define B2_2     38912      // bf16 [8][128] = 2048
#define WB2      40960      // 2 x 49152 group ring -> 139264

__global__ __launch_bounds__(512, 1) void fused_kernel(
    const float* __restrict__ ft, const float* __restrict__ fa, const float* __restrict__ fv,
    const u16* __restrict__ pimg, const float* __restrict__ proj_b,
    const u16* __restrict__ w1img, const u16* __restrict__ w2img,
    const u16* __restrict__ prwT, const u16* __restrict__ gwimg,
    const float* __restrict__ gate_b, const float* __restrict__ exp_b1, const float* __restrict__ exp_b2,
    const float* __restrict__ pre_b, const float* __restrict__ head_w, const float* __restrict__ head_b,
    float* __restrict__ out)
{
    __shared__ __align__(16) char lds[163840];
    const int tid = threadIdx.x;
    const int lane = tid & 63, wid = tid >> 6;   // 8 waves
    const int wr = wid >> 1, wc = wid & 1;       // 4 x 2
    const int lr = lane & 15, q = lane >> 4;
    const int blk = blockIdx.x;
    const int row0 = blk * 128;
    const char* w1b = (const char*)w1img;
    const char* w2b = (const char*)w2img;
    char* HsB = lds + HS2;
    u16* b1L = (u16*)(lds + B1_2);
    u16* b2L = (u16*)(lds + B2_2);

    // ---- prologue: proj_b -> registers, drain so pipeline counts are exact ----
    float pb0[4], pb1[4], pb2[4];
    #pragma unroll
    for (int ni = 0; ni < 4; ni++){
        int c = wc*64 + ni*16 + lr;
        pb0[ni] = proj_b[c];
        pb1[ni] = proj_b[128 + c];
        pb2[ni] = proj_b[256 + c];
    }
    asm volatile("s_waitcnt vmcnt(0)" ::: "memory");

    // A staging source offsets (XOR-pre-swizzled global addresses, linear LDS dst)
    u32 aoffs[2];
    #pragma unroll
    for (int i = 0; i < 2; i++){
        int P = i*8192 + tid*16;
        int row = P >> 7, inner = P & 127;
        aoffs[i] = (u32)((row0 + row)*3072 + (inner ^ ((row & 7) << 4)));
    }

#define ASTAGE(c) do{                                                          \
        int mm_ = (c) / 24, kk_ = (c) % 24;                                    \
        const char* ab_ = (const char*)(mm_ == 0 ? ft : mm_ == 1 ? fa : fv);   \
        char* la_ = lds + A_OFF + ((c) % 3)*16384 + tid*16;                    \
        async_cp16(la_,        ab_ + aoffs[0] + kk_*128);                      \
        async_cp16(la_ + 8192, ab_ + aoffs[1] + kk_*128);                      \
    }while(0)

#define BSTAGE(c) do{                                                          \
        int mm_ = (c) / 24, kk_ = (c) % 24;                                    \
        async_cp16(lds + B_OFF + ((c) % 2)*8192 + tid*16,                      \
                   (const char*)pimg + mm_*196608 + kk_*8192 + tid*16);        \
    }while(0)

#define PCONSUME(c) do{                                                        \
        const char* Abuf = lds + A_OFF + ((c) % 3)*16384;                      \
        const char* Bbuf = lds + B_OFF + ((c) % 2)*8192;                       \
        bf16x8 af[2];                                                          \
        _Pragma("unroll")                                                      \
        for (int mi = 0; mi < 2; mi++){                                        \
            int row = wr*32 + mi*16 + lr;                                      \
            int aoff = row*128 + ((q*32) ^ ((row & 7) << 4));                  \
            f32x4 a0 = *(const f32x4*)(Abuf + aoff);                           \
            f32x4 a1 = *(const f32x4*)(Abuf + (aoff ^ 16));                    \
            union { u32 w[4]; bf16x8 v; } u;                                   \
            u.w[0] = cvtpk(a0.x, a0.y); u.w[1] = cvtpk(a0.z, a0.w);            \
            u.w[2] = cvtpk(a1.x, a1.y); u.w[3] = cvtpk(a1.z, a1.w);            \
            af[mi] = u.v;                                                      \
        }                                                                      \
        __builtin_amdgcn_s_setprio(1);                                         \
        _Pragma("unroll")                                                      \
        for (int ni = 0; ni < 4; ni++){                                        \
            int col = wc*64 + ni*16 + lr;                                      \
            int boff = col*64 + ((q*16) ^ (((col >> 1) & 3) << 4));            \
            bf16x8 bf = *(const bf16x8*)(Bbuf + boff);                         \
            acc[0][ni] = __builtin_amdgcn_mfma_f32_16x16x32_bf16(af[0], bf, acc[0][ni], 0, 0, 0); \
            acc[1][ni] = __builtin_amdgcn_mfma_f32_16x16x32_bf16(af[1], bf, acc[1][ni], 0, 0, 0); \
        }                                                                      \
        __builtin_amdgcn_s_setprio(0);                                         \
    }while(0)

// one modality: 24 chunk iterations + epilogue into Xs image (MC is a literal)
#define PHASE_A_MOD(MC, PB) do{                                                \
        _Pragma("unroll 1")                                                    \
        for (int kt = 0; kt < 24; kt++){                                       \
            int t = MC*24 + kt;                                                \
            __builtin_amdgcn_sched_barrier(0);                                 \
            __builtin_amdgcn_s_barrier();                                      \
            if (t < 71) BSTAGE(t + 1);                                         \
            if (t < 70) ASTAGE(t + 2);                                         \
            if (t < 70)       asm volatile("s_waitcnt vmcnt(5)" ::: "memory"); \
            else if (t == 70) asm volatile("s_waitcnt vmcnt(3)" ::: "memory"); \
            else              asm volatile("s_waitcnt vmcnt(0)" ::: "memory"); \
            __builtin_amdgcn_s_barrier();                                      \
            __builtin_amdgcn_sched_barrier(0);                                 \
            PCONSUME(t);                                                       \
        }                                                                      \
        _Pragma("unroll")                                                      \
        for (int mi = 0; mi < 2; mi++)                                         \
            _Pragma("unroll")                                                  \
            for (int ni = 0; ni < 4; ni++){                                    \
                int lcol = wc*64 + ni*16 + lr;                                 \
                int colg = MC*128 + lcol;                                      \
                int ktI = colg >> 5, qI = (colg >> 3) & 3, el = colg & 7;      \
                _Pragma("unroll")                                              \
                for (int j = 0; j < 4; j++){                                   \
                    int row = wr*32 + mi*16 + q*4 + j;                         \
                    *(u16*)(lds + (row >> 6)*49152 + ktI*4096 + qI*1024        \
                            + (row & 63)*16 + el*2) = f2bf(acc[mi][ni][j] + PB[ni]); \
                    acc[mi][ni][j] = 0.f;                                      \
                }                                                              \
            }                                                                  \
    }while(0)

    f32x4 acc[2][4];
    #pragma unroll
    for (int i = 0; i < 2; i++)
        #pragma unroll
        for (int j = 0; j < 4; j++) acc[i][j] = {0.f, 0.f, 0.f, 0.f};

    BSTAGE(0); ASTAGE(0); ASTAGE(1);
    PHASE_A_MOD(0, pb0);
    PHASE_A_MOD(1, pb1);
    PHASE_A_MOD(2, pb2);
#undef ASTAGE
#undef BSTAGE
#undef PCONSUME
#undef PHASE_A_MOD

    asm volatile("s_waitcnt lgkmcnt(0)" ::: "memory");
    __builtin_amdgcn_sched_barrier(0);
    __builtin_amdgcn_s_barrier();                          // Xs image complete

    // ---- xreg preload + gate: the ONLY readers of Xs ----
    bf16x8 xreg[12][2];
    {
        const char* xa0 = lds + (wr >> 1)*49152 + q*1024;
        #pragma unroll
        for (int ph = 0; ph < 12; ph++){
            xreg[ph][0] = *(const bf16x8*)(xa0 + ph*4096 + ((wr & 1)*32 + lr)*16);
            xreg[ph][1] = *(const bf16x8*)(xa0 + ph*4096 + ((wr & 1)*32 + 16 + lr)*16);
        }
    }
    float gw4[4];
    {
        f32x4 ga = {0.f, 0.f, 0.f, 0.f};
        const char* xb = lds + (wid >> 2)*49152 + ((wid & 3)*16 + lr)*16 + q*1024;
        const u16* gwp = gwimg + lr*384 + q*8;
        #pragma unroll
        for (int kt = 0; kt < 12; kt++){
            bf16x8 af = *(const bf16x8*)(xb + kt*4096);
            bf16x8 gb = *(const bf16x8*)(gwp + kt*32);
            ga = __builtin_amdgcn_mfma_f32_16x16x32_bf16(af, gb, ga, 0, 0, 0);
        }
        float gbv = gate_b[lr & 7];
        #pragma unroll
        for (int j = 0; j < 4; j++){
            float v = ga[j] + gbv;
            float mx = v;
            mx = fmaxf(mx, __shfl_xor(mx, 1));
            mx = fmaxf(mx, __shfl_xor(mx, 2));
            mx = fmaxf(mx, __shfl_xor(mx, 4));
            float s = __expf(v - mx);
            float t = s;
            t += __shfl_xor(t, 1);
            t += __shfl_xor(t, 2);
            t += __shfl_xor(t, 4);
            gw4[j] = s / t;
        }
    }
    asm volatile("s_waitcnt lgkmcnt(0)" ::: "memory");     // all Xs reads retired
    __builtin_amdgcn_sched_barrier(0);
    __builtin_amdgcn_s_barrier();                          // Xs region now dead

    // ---- phase-C group staging: uniform 6 async_cp16 per 48K group ----
#define WGROUP_STAGE3(gg, sl) do{                                              \
        int e3_ = (gg) / 3, p3_ = (gg) % 3;                                    \
        char* dst_ = lds + WB2 + (sl)*49152 + tid*16;                          \
        if (p3_ < 2){                                                          \
            const char* src_ = w1b + e3_*98304 + p3_*49152 + tid*16;           \
            async_cp16(dst_,         src_);                                    \
            async_cp16(dst_ + 8192,  src_ + 8192);                             \
            async_cp16(dst_ + 16384, src_ + 16384);                            \
            async_cp16(dst_ + 24576, src_ + 24576);                            \
            async_cp16(dst_ + 32768, src_ + 32768);                            \
            async_cp16(dst_ + 40960, src_ + 40960);                            \
        } else {                                                               \
            const char* src_ = w2b + e3_*32768 + tid*16;                       \
            async_cp16(dst_,         src_);                                    \
            async_cp16(dst_ + 8192,  src_ + 8192);                             \
            async_cp16(dst_ + 16384, src_ + 16384);                            \
            async_cp16(dst_ + 24576, src_ + 24576);                            \
            async_cp16(dst_ + 32768, src_);   /* dups: uniform vmcnt */        \
            async_cp16(dst_ + 40960, src_);                                    \
        }                                                                      \
    }while(0)

    // GWT/biases + prefetch groups 0,1 into the reclaimed region
    if (lr < 8){
        f32x4 wv = {gw4[0], gw4[1], gw4[2], gw4[3]};
        *(f32x4*)(lds + GWT2 + lr*512 + (wid*16 + q*4)*4) = wv;
    }
    for (int i = tid; i < 1024; i += 512){
        b1L[i] = f2bf(exp_b1[i]);
        b2L[i] = f2bf(exp_b2[i]);
    }
    WGROUP_STAGE3(0, 0);
    WGROUP_STAGE3(1, 1);
    asm volatile("s_waitcnt vmcnt(0) lgkmcnt(0)" ::: "memory");
    __builtin_amdgcn_sched_barrier(0);
    __builtin_amdgcn_s_barrier();

    // ---- phase C: 24 groups (per expert: 2x w1-halves + 1x w2), vmcnt(6) ----
    f32x4 fus[2][4];
    #pragma unroll
    for (int i = 0; i < 2; i++)
        #pragma unroll
        for (int j = 0; j < 4; j++) fus[i][j] = {0.f, 0.f, 0.f, 0.f};

    #pragma unroll 1
    for (int e = 0; e < 8; e++){
        f32x4 ac1[2][4];
        #pragma unroll
        for (int i = 0; i < 2; i++)
            #pragma unroll
            for (int j = 0; j < 4; j++) ac1[i][j] = {0.f, 0.f, 0.f, 0.f};

        // ---- group 3e: w1 ph 0..5 ----
        {
            int g = e*3;
            const char* wbase = lds + WB2 + (g & 1)*49152;
            __builtin_amdgcn_s_setprio(1);
            #pragma unroll
            for (int c = 0; c < 6; c++){
                const char* wsl = wbase + c*8192 + q*2048;
                #pragma unroll
                for (int ni = 0; ni < 4; ni++){
                    bf16x8 bf = *(const bf16x8*)(wsl + (wc*64 + ni*16 + lr)*16);
                    ac1[0][ni] = __builtin_amdgcn_mfma_f32_16x16x32_bf16(xreg[c][0], bf, ac1[0][ni], 0, 0, 0);
                    ac1[1][ni] = __builtin_amdgcn_mfma_f32_16x16x32_bf16(xreg[c][1], bf, ac1[1][ni], 0, 0, 0);
                }
            }
            __builtin_amdgcn_s_setprio(0);
            __builtin_amdgcn_sched_barrier(0);
            __builtin_amdgcn_s_barrier();
            WGROUP_STAGE3(g + 2, (g + 2) & 1);
            asm volatile("s_waitcnt vmcnt(6)" ::: "memory");
            __builtin_amdgcn_s_barrier();
            __builtin_amdgcn_sched_barrier(0);
        }
        // ---- group 3e+1: w1 ph 6..11, then h-write ----
        {
            int g = e*3 + 1;
            const char* wbase = lds + WB2 + (g & 1)*49152;
            __builtin_amdgcn_s_setprio(1);
            #pragma unroll
            for (int c = 0; c < 6; c++){
                const char* wsl = wbase + c*8192 + q*2048;
                #pragma unroll
                for (int ni = 0; ni < 4; ni++){
                    bf16x8 bf = *(const bf16x8*)(wsl + (wc*64 + ni*16 + lr)*16);
                    ac1[0][ni] = __builtin_amdgcn_mfma_f32_16x16x32_bf16(xreg[6 + c][0], bf, ac1[0][ni], 0, 0, 0);
                    ac1[1][ni] = __builtin_amdgcn_mfma_f32_16x16x32_bf16(xreg[6 + c][1], bf, ac1[1][ni], 0, 0, 0);
                }
            }
            __builtin_amdgcn_s_setprio(0);
            // h = relu(ac1 + b1) -> Hs (XOR-swizzled)
            #pragma unroll
            for (int mi = 0; mi < 2; mi++)
                #pragma unroll
                for (int ni = 0; ni < 4; ni++){
                    int col = wc*64 + ni*16 + lr;
                    float b1v = bf2f(b1L[e*128 + col]);
                    #pragma unroll
                    for (int j = 0; j < 4; j++){
                        int row = wr*32 + mi*16 + q*4 + j;
                        *(u16*)(HsB + row*256 + ((col*2) ^ ((row & 7) << 4)))
                            = f2bf(fmaxf(ac1[mi][ni][j] + b1v, 0.f));
                    }
                }
            asm volatile("s_waitcnt lgkmcnt(0)" ::: "memory");
            __builtin_amdgcn_sched_barrier(0);
            __builtin_amdgcn_s_barrier();                  // slot reads + Hs writes done
            WGROUP_STAGE3(g + 2, (g + 2) & 1);
            asm volatile("s_waitcnt vmcnt(6)" ::: "memory");
            __builtin_amdgcn_s_barrier();                  // next group + Hs visible
            __builtin_amdgcn_sched_barrier(0);
        }
        // ---- group 3e+2: w2 (4 chunks) ----
        {
            int g = e*3 + 2;
            const char* wbase = lds + WB2 + (g & 1)*49152;
            f32x4 ac2[2][4];
            #pragma unroll
            for (int i = 0; i < 2; i++)
                #pragma unroll
                for (int j = 0; j < 4; j++) ac2[i][j] = {0.f, 0.f, 0.f, 0.f};
            #pragma unroll
            for (int c = 0; c < 4; c++){
                const char* wsl = wbase + c*8192 + q*2048;
                int cb = c*64 + q*16;
                int rowA = wr*32 + lr;
                int rowB = wr*32 + 16 + lr;
                bf16x8 af0 = *(const bf16x8*)(HsB + rowA*256 + (cb ^ ((rowA & 7) << 4)));
                bf16x8 af1 = *(const bf16x8*)(HsB + rowB*256 + (cb ^ ((rowB & 7) << 4)));
                __builtin_amdgcn_s_setprio(1);
                #pragma unroll
                for (int ni = 0; ni < 4; ni++){
                    bf16x8 bf = *(const bf16x8*)(wsl + (wc*64 + ni*16 + lr)*16);
                    ac2[0][ni] = __builtin_amdgcn_mfma_f32_16x16x32_bf16(af0, bf, ac2[0][ni], 0, 0, 0);
                    ac2[1][ni] = __builtin_amdgcn_mfma_f32_16x16x32_bf16(af1, bf, ac2[1][ni], 0, 0, 0);
                }
                __builtin_amdgcn_s_setprio(0);
            }
            __builtin_amdgcn_sched_barrier(0);
            __builtin_amdgcn_s_barrier();                  // slot reads done
            {
                int gn = g + 2;
                if (gn < 24){
                    WGROUP_STAGE3(gn, gn & 1);
                    asm volatile("s_waitcnt vmcnt(6)" ::: "memory");
                } else {
                    asm volatile("s_waitcnt vmcnt(0)" ::: "memory");
                }
            }
            __builtin_amdgcn_s_barrier();
            __builtin_amdgcn_sched_barrier(0);
            // fused += gw[:,e] * (eo + b2)
            #pragma unroll
            for (int mi = 0; mi < 2; mi++){
                f32x4 gwv = *(const f32x4*)(lds + GWT2 + e*512 + (wr*32 + mi*16 + q*4)*4);
                #pragma unroll
                for (int ni = 0; ni < 4; ni++){
                    int col = wc*64 + ni*16 + lr;
                    float b2v = bf2f(b2L[e*128 + col]);
                    #pragma unroll
                    for (int j = 0; j < 4; j++)
                        fus[mi][ni][j] += gwv[j] * (ac2[mi][ni][j] + b2v);
                }
            }
        }
    }
#undef WGROUP_STAGE3

    __builtin_amdgcn_sched_barrier(0);
    __builtin_amdgcn_s_barrier();                      // all Hs(h7) reads done
    // fused -> Hs (bf16, XOR-swizzled)
    #pragma unroll
    for (int mi = 0; mi < 2; mi++)
        #pragma unroll
        for (int ni = 0; ni < 4; ni++){
            int col = wc*64 + ni*16 + lr;
            #pragma unroll
            for (int j = 0; j < 4; j++){
                int row = wr*32 + mi*16 + q*4 + j;
                *(u16*)(HsB + row*256 + ((col*2) ^ ((row & 7) << 4))) = f2bf(fus[mi][ni][j]);
            }
        }
    asm volatile("s_waitcnt lgkmcnt(0)" ::: "memory");
    __builtin_amdgcn_sched_barrier(0);
    __builtin_amdgcn_s_barrier();

    // ---- penult = relu(fused @ pre_w + pre_b): wave wid -> rows wid*16..+16 ----
    f32x4 ap[4];
    #pragma unroll
    for (int i = 0; i < 4; i++) ap[i] = {0.f, 0.f, 0.f, 0.f};
    #pragma unroll
    for (int kt = 0; kt < 4; kt++){
        int row = wid*16 + lr;
        int cb = kt*64 + q*16;
        bf16x8 af = *(const bf16x8*)(HsB + row*256 + (cb ^ ((row & 7) << 4)));
        #pragma unroll
        for (int ni = 0; ni < 4; ni++){
            bf16x8 bf = *(const bf16x8*)(prwT + (size_t)(ni*16 + lr)*128 + kt*32 + q*8);
            ap[ni] = __builtin_amdgcn_mfma_f32_16x16x32_bf16(af, bf, ap[ni], 0, 0, 0);
        }
    }
    float* Pen = (float*)(lds + WB2);   // [128][68], WB region dead
    #pragma unroll
    for (int ni = 0; ni < 4; ni++){
        int col = ni*16 + lr;
        float pbv = pre_b[col];
        #pragma unroll
        for (int j = 0; j < 4; j++){
            int row = wid*16 + q*4 + j;
            Pen[row*68 + col] = fmaxf(ap[ni][j] + pbv, 0.f);
        }
    }
    asm volatile("s_waitcnt lgkmcnt(0)" ::: "memory");
    __builtin_amdgcn_sched_barrier(0);
    __builtin_amdgcn_s_barrier();
    // ---- head ----
    if (tid < 256){
        int r = tid >> 1, c = tid & 1;
        float s = head_b[c];
        #pragma unroll 8
        for (int k = 0; k < 64; k++) s += Pen[r*68 + k] * head_w[k*2 + c];
        out[(size_t)(blk*128 + r)*2 + c] = s;
    }
}

extern "C" void kernel_launch(void* const* d_in, const int* in_sizes, int n_in,
                              void* d_out, int out_size, void* d_ws, size_t ws_size,
                              hipStream_t stream) {
    const float* ft     = (const float*)d_in[0];
    const float* fa     = (const float*)d_in[1];
    const float* fv     = (const float*)d_in[2];
    const float* proj_w = (const float*)d_in[3];
    const float* proj_b = (const float*)d_in[4];
    const float* exp_w1 = (const float*)d_in[5];
    const float* exp_b1 = (const float*)d_in[6];
    const float* exp_w2 = (const float*)d_in[7];
    const float* exp_b2 = (const float*)d_in[8];
    const float* gate_w = (const float*)d_in[9];
    const float* gate_b = (const float*)d_in[10];
    const float* pre_w  = (const float*)d_in[11];
    const float* pre_b  = (const float*)d_in[12];
    const float* head_w = (const float*)d_in[13];
    const float* head_b = (const float*)d_in[14];
    float* out = (float*)d_out;

    u16* pimg  = (u16*)d_ws;                      // 294912
    u16* w1img = pimg + 294912;                   // 393216
    u16* w2img = w1img + 393216;                  // 131072
    u16* prwT  = w2img + 131072;                  // 8192
    u16* gwimg = prwT + 8192;                     // 6144

    cast_weights_kernel<<<3256, 256, 0, stream>>>(proj_w, exp_w1, exp_w2, pre_w, gate_w,
                                                  pimg, w1img, w2img, prwT, gwimg);
    fused_kernel<<<256, 512, 0, stream>>>(ft, fa, fv, pimg, proj_b,
                                          w1img, w2img, prwT, gwimg,
                                          gate_b, exp_b1, exp_b2,
                                          pre_b, head_w, head_b, out);
}